// Round 1
// baseline (168.175 us; speedup 1.0000x reference)
//
#include <hip/hip_runtime.h>
#include <math.h>

#define PAIRS 32      // (c,a) pairs per block
#define BLOCK 256
#define NCOEF 45
#define NOUT  165     // 9 s + 12 dist + 144 angles
#define NVEC  12

// Input coefficient index for orbital vector k (0..11), component c (0..2).
// k<4: p rows -> 9+3k+c.  k>=4: q=k-4, idx = 21 + 6*(q/2) + D_REORDER[(q%2)*3+c],
// D_REORDER = {0,2,5,4,3,1}.
__constant__ int C_IDX[NVEC][3] = {
    { 9, 10, 11}, {12, 13, 14}, {15, 16, 17}, {18, 19, 20},
    {21, 23, 26}, {25, 24, 22},
    {27, 29, 32}, {31, 30, 28},
    {33, 35, 38}, {37, 36, 34},
    {39, 41, 44}, {43, 42, 40}
};

// 66 upper-triangle (i<j) pairs packed (i<<4)|j, row-major order.
__constant__ unsigned char C_UPAIR[66] = {
    0x01,0x02,0x03,0x04,0x05,0x06,0x07,0x08,0x09,0x0A,0x0B,
    0x12,0x13,0x14,0x15,0x16,0x17,0x18,0x19,0x1A,0x1B,
    0x23,0x24,0x25,0x26,0x27,0x28,0x29,0x2A,0x2B,
    0x34,0x35,0x36,0x37,0x38,0x39,0x3A,0x3B,
    0x45,0x46,0x47,0x48,0x49,0x4A,0x4B,
    0x56,0x57,0x58,0x59,0x5A,0x5B,
    0x67,0x68,0x69,0x6A,0x6B,
    0x78,0x79,0x7A,0x7B,
    0x89,0x8A,0x8B,
    0x9A,0x9B,
    0xAB
};

__global__ __launch_bounds__(BLOCK) void aev_kernel(const float* __restrict__ in,
                                                    float* __restrict__ out,
                                                    int npairs) {
    __shared__ float s_in [PAIRS * NCOEF];      // 1440 f32
    __shared__ float s_n  [PAIRS * NVEC * 3];   // 1152 f32 (normalized vectors)
    __shared__ float s_out[PAIRS * NOUT];       // 5280 f32

    const int tid = threadIdx.x;
    const long long base = (long long)blockIdx.x * PAIRS;
    const int valid = (npairs - (int)base) < PAIRS ? (npairs - (int)base) : PAIRS;
    const float* gin  = in  + base * NCOEF;
    float*       gout = out + base * NOUT;

    // --- coalesced input load ---
    for (int i = tid; i < valid * NCOEF; i += BLOCK)
        s_in[i] = gin[i];

    // --- zero-fill angle region (independent of input) ---
    for (int i = tid; i < valid * 144; i += BLOCK) {
        int p = i / 144, e = i % 144;
        s_out[p * NOUT + 21 + e] = 0.0f;
    }
    __syncthreads();

    // --- s-coeff copy ---
    for (int i = tid; i < valid * 9; i += BLOCK) {
        int p = i / 9, c = i % 9;
        s_out[p * NOUT + c] = s_in[p * NCOEF + c];
    }
    // --- norms + normalized vectors (384 tasks) ---
    for (int t = tid; t < valid * NVEC; t += BLOCK) {
        int p = t / NVEC, k = t % NVEC;
        const float* sp = &s_in[p * NCOEF];
        float x = sp[C_IDX[k][0]];
        float y = sp[C_IDX[k][1]];
        float z = sp[C_IDX[k][2]];
        float d = sqrtf(x * x + y * y + z * z);
        float invd = 1.0f / d;
        s_out[p * NOUT + 9 + k] = d;
        float* np_ = &s_n[(p * NVEC + k) * 3];
        np_[0] = x * invd;
        np_[1] = y * invd;
        np_[2] = z * invd;
    }
    __syncthreads();

    // --- 66 upper-triangle angles per pair (2112 tasks) ---
    for (int t = tid; t < valid * 66; t += BLOCK) {
        int p = t / 66, u = t % 66;
        int ij = C_UPAIR[u];
        int i = ij >> 4, j = ij & 15;
        const float* ni = &s_n[(p * NVEC + i) * 3];
        const float* nj = &s_n[(p * NVEC + j) * 3];
        float dot = ni[0] * nj[0] + ni[1] * nj[1] + ni[2] * nj[2];
        s_out[p * NOUT + 21 + i * 12 + j] = acosf(0.95f * dot);
    }
    __syncthreads();

    // --- coalesced output store ---
    for (int i = tid; i < valid * NOUT; i += BLOCK)
        gout[i] = s_out[i];
}

extern "C" void kernel_launch(void* const* d_in, const int* in_sizes, int n_in,
                              void* d_out, int out_size, void* d_ws, size_t ws_size,
                              hipStream_t stream) {
    const float* coeff = (const float*)d_in[0];
    float* out = (float*)d_out;
    int npairs = in_sizes[0] / NCOEF;           // 4096*128 = 524288
    int grid = (npairs + PAIRS - 1) / PAIRS;    // 16384
    aev_kernel<<<grid, BLOCK, 0, stream>>>(coeff, out, npairs);
}

// Round 2
// 157.101 us; speedup vs baseline: 1.0705x; 1.0705x over previous
//
#include <hip/hip_runtime.h>
#include <math.h>

#define PAIRS 32      // (c,a) pairs per block (npairs % PAIRS == 0 for this problem)
#define BLOCK 256
#define NCOEF 45
#define NOUT  165     // 9 s + 12 dist + 144 angles
#define NVEC  12

// Packed input coefficient indices for orbital vector k: c0 | c1<<8 | c2<<16.
// k<4: p rows -> 9+3k+c.  k>=4: q=k-4, idx = 21 + 6*(q/2) + D_REORDER[(q%2)*3+c],
// D_REORDER = {0,2,5,4,3,1}.
__constant__ int C_IDX3[NVEC] = {
    9 | (10 << 8) | (11 << 16),
    12 | (13 << 8) | (14 << 16),
    15 | (16 << 8) | (17 << 16),
    18 | (19 << 8) | (20 << 16),
    21 | (23 << 8) | (26 << 16),
    25 | (24 << 8) | (22 << 16),
    27 | (29 << 8) | (32 << 16),
    31 | (30 << 8) | (28 << 16),
    33 | (35 << 8) | (38 << 16),
    37 | (36 << 8) | (34 << 16),
    39 | (41 << 8) | (44 << 16),
    43 | (42 << 8) | (40 << 16)
};

// 66 upper-triangle (i<j) pairs packed (i<<4)|j, row-major order.
__constant__ unsigned char C_UPAIR[66] = {
    0x01,0x02,0x03,0x04,0x05,0x06,0x07,0x08,0x09,0x0A,0x0B,
    0x12,0x13,0x14,0x15,0x16,0x17,0x18,0x19,0x1A,0x1B,
    0x23,0x24,0x25,0x26,0x27,0x28,0x29,0x2A,0x2B,
    0x34,0x35,0x36,0x37,0x38,0x39,0x3A,0x3B,
    0x45,0x46,0x47,0x48,0x49,0x4A,0x4B,
    0x56,0x57,0x58,0x59,0x5A,0x5B,
    0x67,0x68,0x69,0x6A,0x6B,
    0x78,0x79,0x7A,0x7B,
    0x89,0x8A,0x8B,
    0x9A,0x9B,
    0xAB
};

// Classic minimax: |err| <= 6.8e-5 on [-1,1]; branch-free reflection.
__device__ __forceinline__ float fast_acos(float x) {
    float ax = fabsf(x);
    float r = fmaf(-0.0187293f, ax, 0.0742610f);
    r = fmaf(r, ax, -0.2121144f);
    r = fmaf(r, ax, 1.5707288f);
    r *= sqrtf(1.0f - ax);
    return x < 0.0f ? 3.14159265358979f - r : r;
}

__global__ __launch_bounds__(BLOCK) void aev_kernel(const float4* __restrict__ in4,
                                                    float4* __restrict__ out4) {
    __shared__ float  s_in [PAIRS * NCOEF];      // 1440 f32 = 5.76 KB
    __shared__ float4 s_n4 [PAIRS * NVEC];       // 384 float4 = 6 KB
    __shared__ float  s_out[PAIRS * NOUT];       // 5280 f32 = 21.1 KB

    const int tid = threadIdx.x;
    const size_t blk = blockIdx.x;

    // --- coalesced float4 input load (360 per block) ---
    const float4* gi = in4 + blk * (PAIRS * NCOEF / 4);
    float4* s_in4 = (float4*)s_in;
    for (int i = tid; i < PAIRS * NCOEF / 4; i += BLOCK)
        s_in4[i] = gi[i];

    // --- zero-fill whole staging output (1320 float4) ---
    float4* s_out4 = (float4*)s_out;
    const float4 z4 = make_float4(0.f, 0.f, 0.f, 0.f);
    for (int i = tid; i < PAIRS * NOUT / 4; i += BLOCK)
        s_out4[i] = z4;
    __syncthreads();

    // --- s-coeff copy (288 tasks) ---
    for (int i = tid; i < PAIRS * 9; i += BLOCK) {
        int p = i / 9, c = i - p * 9;
        s_out[p * NOUT + c] = s_in[p * NCOEF + c];
    }

    // --- norms + normalized vectors (384 tasks) ---
    for (int t = tid; t < PAIRS * NVEC; t += BLOCK) {
        int p = t / NVEC, k = t - p * NVEC;
        int pk = C_IDX3[k];
        const float* sp = &s_in[p * NCOEF];
        float x = sp[pk & 255];
        float y = sp[(pk >> 8) & 255];
        float z = sp[(pk >> 16) & 255];
        float s = fmaf(x, x, fmaf(y, y, z * z));
        float inv = rsqrtf(s);
        s_out[p * NOUT + 9 + k] = s * inv;     // distance = s * rsqrt(s)
        s_n4[p * NVEC + k] = make_float4(x * inv, y * inv, z * inv, 0.f);
    }
    __syncthreads();

    // --- 66 upper-triangle angles per pair (2112 tasks) ---
    for (int t = tid; t < PAIRS * 66; t += BLOCK) {
        int p = t / 66, u = t - p * 66;
        int ij = C_UPAIR[u];
        int i = ij >> 4, j = ij & 15;
        float4 a = s_n4[p * NVEC + i];
        float4 b = s_n4[p * NVEC + j];
        float dot = fmaf(a.x, b.x, fmaf(a.y, b.y, a.z * b.z));
        s_out[p * NOUT + 21 + i * 12 + j] = fast_acos(0.95f * dot);
    }
    __syncthreads();

    // --- coalesced float4 output store (1320 per block) ---
    float4* go = out4 + blk * (PAIRS * NOUT / 4);
    for (int i = tid; i < PAIRS * NOUT / 4; i += BLOCK)
        go[i] = s_out4[i];
}

extern "C" void kernel_launch(void* const* d_in, const int* in_sizes, int n_in,
                              void* d_out, int out_size, void* d_ws, size_t ws_size,
                              hipStream_t stream) {
    const float4* coeff = (const float4*)d_in[0];
    float4* out = (float4*)d_out;
    int npairs = in_sizes[0] / NCOEF;           // 4096*128 = 524288, % PAIRS == 0
    int grid = npairs / PAIRS;                  // 16384
    aev_kernel<<<grid, BLOCK, 0, stream>>>(coeff, out);
}

// Round 4
// 67.095 us; speedup vs baseline: 2.5065x; 2.3415x over previous
//
#include <hip/hip_runtime.h>
#include <math.h>

#define PAIRS 16      // (c,a) pairs per block; 16 threads per pair
#define BLOCK 256
#define NCOEF 45
#define NOUT  165     // 9 s + 12 dist + 144 angles
#define NVEC  12

typedef float f32x4 __attribute__((ext_vector_type(4)));

// 66 upper-triangle (i<j) pairs packed (i<<4)|j, row-major order.
__constant__ unsigned char C_UPAIR[66] = {
    0x01,0x02,0x03,0x04,0x05,0x06,0x07,0x08,0x09,0x0A,0x0B,
    0x12,0x13,0x14,0x15,0x16,0x17,0x18,0x19,0x1A,0x1B,
    0x23,0x24,0x25,0x26,0x27,0x28,0x29,0x2A,0x2B,
    0x34,0x35,0x36,0x37,0x38,0x39,0x3A,0x3B,
    0x45,0x46,0x47,0x48,0x49,0x4A,0x4B,
    0x56,0x57,0x58,0x59,0x5A,0x5B,
    0x67,0x68,0x69,0x6A,0x6B,
    0x78,0x79,0x7A,0x7B,
    0x89,0x8A,0x8B,
    0x9A,0x9B,
    0xAB
};

// Minimax acos: |err| <= 6.8e-5 on [-1,1]; branch-free reflection.
__device__ __forceinline__ float fast_acos(float x) {
    float ax = fabsf(x);
    float r = fmaf(-0.0187293f, ax, 0.0742610f);
    r = fmaf(r, ax, -0.2121144f);
    r = fmaf(r, ax, 1.5707288f);
    r *= sqrtf(1.0f - ax);
    return x < 0.0f ? 3.14159265358979f - r : r;
}

__global__ __launch_bounds__(BLOCK) void aev_kernel(const f32x4* __restrict__ in4,
                                                    f32x4* __restrict__ out4) {
    __shared__ float  s_in [PAIRS * NCOEF];      // 720 f32  = 2.88 KB
    __shared__ f32x4  s_n4 [PAIRS * NVEC];       // 192 f4   = 3 KB
    __shared__ float  s_out[PAIRS * NOUT];       // 2640 f32 = 10.56 KB
    __shared__ unsigned char s_ij[68];           // (i,j) pair table

    const int tid = threadIdx.x;
    const int grp = tid >> 4;      // pair 0..15
    const int ln  = tid & 15;      // lane within pair
    const size_t blk = blockIdx.x;

    // --- phase 0: load input (180 f4), copy pair table, zero staging ---
    const f32x4* gi = in4 + blk * (PAIRS * NCOEF / 4);
    f32x4* s_in4 = (f32x4*)s_in;
    if (tid < PAIRS * NCOEF / 4) s_in4[tid] = gi[tid];
    if (tid < 66) s_ij[tid] = C_UPAIR[tid];
    f32x4* s_out4 = (f32x4*)s_out;
    const f32x4 z4 = {0.f, 0.f, 0.f, 0.f};
    for (int i = tid; i < PAIRS * NOUT / 4; i += BLOCK)   // 660 f4
        s_out4[i] = z4;
    __syncthreads();

    // --- phase 1: s-copy + norms (no divides, no tables) ---
    if (ln < 9)
        s_out[grp * NOUT + ln] = s_in[grp * NCOEF + ln];
    if (ln < NVEC) {
        int k = ln, q = k - 4;
        int base = (k < 4) ? (9 + 3 * k) : (21 + 6 * (q >> 1));
        int odd = (k >= 4) && (q & 1);
        const float* sp = &s_in[grp * NCOEF + base];
        float x = sp[odd ? 4 : 0];
        float y = sp[odd ? 3 : (k < 4 ? 1 : 2)];
        float z = sp[odd ? 1 : (k < 4 ? 2 : 5)];
        float s2 = fmaf(x, x, fmaf(y, y, z * z));
        float inv = rsqrtf(s2);
        s_out[grp * NOUT + 9 + k] = s2 * inv;            // distance
        f32x4 nv = {x * inv, y * inv, z * inv, 0.f};
        s_n4[grp * NVEC + k] = nv;
    }
    __syncthreads();

    // --- phase 2: 66 angles per pair, 16 lanes x 5 unrolled slots ---
    #pragma unroll
    for (int s = 0; s < 5; ++s) {
        int u = ln + (s << 4);
        if (u < 66) {
            int ij = s_ij[u];
            int i = ij >> 4, j = ij & 15;
            f32x4 a = s_n4[grp * NVEC + i];
            f32x4 b = s_n4[grp * NVEC + j];
            float dot = fmaf(a.x, b.x, fmaf(a.y, b.y, a.z * b.z));
            s_out[grp * NOUT + 21 + i * 12 + j] = fast_acos(0.95f * dot);
        }
    }
    __syncthreads();

    // --- phase 3: coalesced nontemporal store (660 f4) ---
    f32x4* go = out4 + blk * (PAIRS * NOUT / 4);
    for (int i = tid; i < PAIRS * NOUT / 4; i += BLOCK)
        __builtin_nontemporal_store(s_out4[i], &go[i]);
}

extern "C" void kernel_launch(void* const* d_in, const int* in_sizes, int n_in,
                              void* d_out, int out_size, void* d_ws, size_t ws_size,
                              hipStream_t stream) {
    const f32x4* coeff = (const f32x4*)d_in[0];
    f32x4* out = (f32x4*)d_out;
    int npairs = in_sizes[0] / NCOEF;           // 4096*128 = 524288
    int grid = npairs / PAIRS;                  // 32768
    aev_kernel<<<grid, BLOCK, 0, stream>>>(coeff, out);
}